// Round 14
// baseline (247.677 us; speedup 1.0000x reference)
//
#include <hip/hip_runtime.h>
#include <stdint.h>

#define IN_DIM 1024
#define H_DIM  1024
#define BATCH  8192
#define KDIM   2048   // IN + H
#define NDIM   4096   // 4*H
#define BM     256
#define BN     256
#define BK     32
#define NT     (KDIM / BK)   // 64 K-tiles

typedef __bf16 bf16x8 __attribute__((ext_vector_type(8)));
typedef float  f32x4  __attribute__((ext_vector_type(4)));
typedef unsigned int u32;

static __device__ __forceinline__ unsigned short f2bf(float f) {
  u32 u = __builtin_bit_cast(u32, f);
  u += 0x7FFFu + ((u >> 16) & 1u);   // round-to-nearest-even
  return (unsigned short)(u >> 16);
}

static __device__ __forceinline__ float sigm(float x) {
  return 1.0f / (1.0f + __expf(-x));
}
static __device__ __forceinline__ float tanh_fast(float x) {
  float e = __expf(-2.0f * fabsf(x));     // in (0,1], no overflow
  float t = (1.0f - e) / (1.0f + e);
  return copysignf(t, x);
}

// ---- fused prep: one dispatch does A-convert, Bt-permute, bias (R12) ----
__global__ void prep_all(const float* __restrict__ x, const float* __restrict__ h,
                         const float* __restrict__ Wi, const float* __restrict__ Wh,
                         const float* __restrict__ bi, const float* __restrict__ bh,
                         unsigned short* __restrict__ A,
                         unsigned short* __restrict__ Bt,
                         float* __restrict__ bias) {
  __shared__ float tile[32][33];
  const int b = blockIdx.x;
  const int t = threadIdx.x;

  if (b < 2048) {
    const int total = BATCH * KDIM / 4;
    for (int i = b * 256 + t; i < total; i += 2048 * 256) {
      int bb = i >> 9;             // 512 quads per row
      int k = (i & 511) << 2;
      const float* src = (k < IN_DIM) ? (x + (size_t)bb * IN_DIM + k)
                                      : (h + (size_t)bb * H_DIM + (k - IN_DIM));
      float4 v = *reinterpret_cast<const float4*>(src);
      ushort4 o;
      o.x = f2bf(v.x); o.y = f2bf(v.y); o.z = f2bf(v.z); o.w = f2bf(v.w);
      *reinterpret_cast<ushort4*>(A + (size_t)bb * KDIM + k) = o;
    }
  } else if (b < 10240) {
    int bb = b - 2048;
    int k0 = (bb & 63) * 32;           // k of combined [Wi;Wh]
    int c0 = (bb >> 6) * 32;           // orig col
    int tx = t & 31;
    int ty = t >> 5;                   // 0..7
    const float* src = (k0 < IN_DIM) ? (Wi + (size_t)k0 * NDIM)
                                     : (Wh + (size_t)(k0 - IN_DIM) * NDIM);
    for (int i = 0; i < 4; i++) {
      int r = ty + 8 * i;
      tile[r][tx] = src[(size_t)r * NDIM + c0 + tx];
    }
    __syncthreads();
    int g = c0 >> 10;                  // gate index (tile doesn't straddle)
    int ubase = c0 & 1023;
    for (int i = 0; i < 4; i++) {
      int cc = ty + 8 * i;
      int u = ubase + cc;
      int j = ((u >> 4) << 6) + (g << 4) + (u & 15);
      Bt[(size_t)j * KDIM + k0 + tx] = f2bf(tile[tx][cc]);
    }
  } else {
    int j = (b - 10240) * 256 + t;     // < 4096
    int u = ((j >> 6) << 4) + (j & 15);
    int g = (j >> 4) & 3;
    int c = (g << 10) + u;
    bias[j] = bi[c] + bh[c];
  }
}

// -- 256x256 GEMM, fat-wave (128x128/wave, 4 waves), BK=32, 2-barrier (R14) --
static __device__ __forceinline__ void gload_lds16(const void* g, void* l) {
  __builtin_amdgcn_global_load_lds(
      (const __attribute__((address_space(1))) u32*)g,
      (__attribute__((address_space(3))) u32*)l, 16, 0, 0);
}

#define MFMA __builtin_amdgcn_mfma_f32_16x16x32_bf16
#define SGB  __builtin_amdgcn_sched_group_barrier
// LLVM SchedGroupMask: MFMA=0x8, DS_READ=0x100

__launch_bounds__(256, 1)
__global__ void lstm_gemm(const unsigned short* __restrict__ A,
                          const unsigned short* __restrict__ Bt,
                          const float* __restrict__ bias,
                          const float* __restrict__ Cin,
                          float* __restrict__ Hout,
                          float* __restrict__ Cout) {
  // LDS: A [2 buf][256 rows][64B] = 32K | B same = 32K   (64 KiB)
  __shared__ __align__(16) char smem[65536];

  const int t  = threadIdx.x;
  const int l  = t & 63;
  const int w  = t >> 6;           // wave 0-3
  const int lane16 = l & 15;
  const int kg = l >> 4;           // 0-3
  const int wr = w >> 1;           // 0-1 (M half)
  const int wc = w & 1;            // 0-1 (N half)

  int bid = blockIdx.x;            // 512 blocks (32 M-tiles x 16 N-tiles)
  int swz = (bid & 7) * 64 + (bid >> 3);   // bijective XCD swizzle (512%8==0)
  int brow = (swz >> 4) * BM;
  int tile_n = swz & 15;
  int bcol = tile_n * BN;          // Bt row base (gate-contig cols)

  // ---- staging: thread t writes LDS linear (seg*4096 + t*16); within a
  //      64-row segment: row = t>>2, LDS chunk slot = t&3; global source
  //      chunk pre-swizzled cth = (t&3) ^ ((t>>3)&3)  [= slot ^ (row>>1)&3] --
  const int cth = (t & 3) ^ ((t >> 3) & 3);
  const int strow = t >> 2;        // 0..63
  const unsigned short* aq0 = A + (size_t)(brow +   0 + strow) * KDIM + cth * 8;
  const unsigned short* aq1 = A + (size_t)(brow +  64 + strow) * KDIM + cth * 8;
  const unsigned short* aq2 = A + (size_t)(brow + 128 + strow) * KDIM + cth * 8;
  const unsigned short* aq3 = A + (size_t)(brow + 192 + strow) * KDIM + cth * 8;
  const unsigned short* bq0 = Bt + (size_t)(bcol +   0 + strow) * KDIM + cth * 8;
  const unsigned short* bq1 = Bt + (size_t)(bcol +  64 + strow) * KDIM + cth * 8;
  const unsigned short* bq2 = Bt + (size_t)(bcol + 128 + strow) * KDIM + cth * 8;
  const unsigned short* bq3 = Bt + (size_t)(bcol + 192 + strow) * KDIM + cth * 8;

#define GL(gp, loff) gload_lds16((gp), smem + (loff) + t * 16)

  // ---- per-lane ds_read bases: read row = {wr,wc}*128 + f*16 + lane16,
  //      chunk slot = kg ^ ((lane16>>1)&3)  (2-way max = free, R13-verified) --
  const int rsw = ((kg ^ ((lane16 >> 1) & 3)) << 4);
  char* vA = smem + (wr * 128 + lane16) * 64 + rsw;           // +P*16384 + m*1024
  char* vB = smem + 32768 + (wc * 128 + lane16) * 64 + rsw;   // +P*16384 + n*1024

  f32x4 acc[8][8];
#pragma unroll
  for (int m = 0; m < 8; m++)
#pragma unroll
    for (int n = 0; n < 8; n++) acc[m][n] = (f32x4){0.f, 0.f, 0.f, 0.f};

  // ---- prologue: tile0 -> buf0, tile1 -> buf1 (8 GL each) ----
  GL(aq0, 0);      GL(aq1, 4096);      GL(aq2, 8192);      GL(aq3, 12288);
  GL(bq0, 32768);  GL(bq1, 32768+4096);GL(bq2, 32768+8192);GL(bq3, 32768+12288);
  GL(aq0+32, 16384);       GL(aq1+32, 16384+4096);
  GL(aq2+32, 16384+8192);  GL(aq3+32, 16384+12288);
  GL(bq0+32, 49152);       GL(bq1+32, 49152+4096);
  GL(bq2+32, 49152+8192);  GL(bq3+32, 49152+12288);
  asm volatile("s_waitcnt vmcnt(8)" ::: "memory");   // tile0 landed
  __builtin_amdgcn_s_barrier();
  __builtin_amdgcn_sched_barrier(0);
  // roll pointers to tile 2 (stage distance 2)
  aq0 += 64; aq1 += 64; aq2 += 64; aq3 += 64;
  bq0 += 64; bq1 += 64; bq2 += 64; bq3 += 64;

  bf16x8 afr[8], bfr[8];

  // ---- 2-barrier K-tile body. Q1: 16 ds_read ∥ 32 MFMA (n0-3); lgkm(0)
  //      (all frags in regs) -> bar_A; S: stage t+2 -> buf P (WAR safe: reads
  //      executed pre-bar_A); Q2: 32 MFMA (n4-7); vmcnt(8) drains tile t+1
  //      exactly (FIFO: [t+1 x8, t+2 x8] outstanding) -> bar_B.
#define BODY(P)                                                              \
  {                                                                          \
    __builtin_amdgcn_s_setprio(1);                                           \
    bfr[0] = *(const bf16x8*)(vB + (P)*16384);                               \
    _Pragma("unroll") for (int mm = 0; mm < 8; mm++)                         \
      afr[mm] = *(const bf16x8*)(vA + (P)*16384 + mm*1024);                  \
    _Pragma("unroll") for (int nn = 1; nn < 8; nn++)                         \
      bfr[nn] = *(const bf16x8*)(vB + (P)*16384 + nn*1024);                  \
    _Pragma("unroll") for (int nn = 0; nn < 4; nn++)                         \
      _Pragma("unroll") for (int mm = 0; mm < 8; mm++)                       \
        acc[mm][nn] = MFMA(afr[mm], bfr[nn], acc[mm][nn], 0, 0, 0);          \
    SGB(0x100, 2, 0); SGB(0x8, 4, 0);                                        \
    SGB(0x100, 2, 0); SGB(0x8, 4, 0);                                        \
    SGB(0x100, 2, 0); SGB(0x8, 4, 0);                                        \
    SGB(0x100, 2, 0); SGB(0x8, 4, 0);                                        \
    SGB(0x100, 2, 0); SGB(0x8, 4, 0);                                        \
    SGB(0x100, 2, 0); SGB(0x8, 4, 0);                                        \
    SGB(0x100, 2, 0); SGB(0x8, 4, 0);                                        \
    SGB(0x100, 2, 0); SGB(0x8, 4, 0);                                        \
    __builtin_amdgcn_s_setprio(0);                                           \
    asm volatile("s_waitcnt lgkmcnt(0)" ::: "memory");                       \
    __builtin_amdgcn_s_barrier();          /* bar_A */                       \
    __builtin_amdgcn_sched_barrier(0);                                       \
    /* S: stage tile t+2 -> buf P */                                         \
    GL(aq0, (P)*16384);          GL(aq1, (P)*16384 + 4096);                  \
    GL(aq2, (P)*16384 + 8192);   GL(aq3, (P)*16384 + 12288);                 \
    GL(bq0, 32768 + (P)*16384);         GL(bq1, 32768 + (P)*16384 + 4096);   \
    GL(bq2, 32768 + (P)*16384 + 8192);  GL(bq3, 32768 + (P)*16384 + 12288);  \
    /* Q2: 32 MFMA (n4-7), register-only */                                  \
    __builtin_amdgcn_s_setprio(1);                                           \
    _Pragma("unroll") for (int nn = 4; nn < 8; nn++)                         \
      _Pragma("unroll") for (int mm = 0; mm < 8; mm++)                       \
        acc[mm][nn] = MFMA(afr[mm], bfr[nn], acc[mm][nn], 0, 0, 0);          \
    __builtin_amdgcn_s_setprio(0);                                           \
    asm volatile("s_waitcnt vmcnt(8)" ::: "memory");                         \
    __builtin_amdgcn_s_barrier();          /* bar_B */                       \
    __builtin_amdgcn_sched_barrier(0);                                       \
    aq0 += 32; aq1 += 32; aq2 += 32; aq3 += 32;                              \
    bq0 += 32; bq1 += 32; bq2 += 32; bq3 += 32;                              \
  }

  for (int it = 0; it < NT / 2; ++it) {
    BODY(0)
    BODY(1)
  }
#undef BODY
#undef GL

  // ---- drain outstanding staging loads (also orders Cin/bias below) ----
  asm volatile("s_waitcnt vmcnt(0)" ::: "memory");

  // ---- epilogue: lane owns all 4 gates of TWO units (n0-3 -> U0, n4-7 -> U1)
  const int U0 = (tile_n * 4 + wc * 2) * 16 + lane16;   // n>>2 == 0
  const int U1 = U0 + 16;                               // n>>2 == 1
  float bv[8];
#pragma unroll
  for (int nn = 0; nn < 8; nn++)
    bv[nn] = bias[tile_n * 256 + wc * 128 + nn * 16 + lane16];

  const int rb = brow + wr * 128 + kg * 4;
  const float* cinp = Cin + (size_t)rb * H_DIM;
  float* hp = Hout + (size_t)rb * H_DIM;
  float* cp = Cout + (size_t)rb * H_DIM;
#pragma unroll
  for (int m = 0; m < 8; m++)
#pragma unroll
    for (int r = 0; r < 4; r++) {
      size_t off = (size_t)(m * 16 + r) * H_DIM;
      // unit 0 (n0..3 = I,F,G,O)
      {
        float Ig = sigm(acc[m][0][r] + bv[0]);
        float Fg = sigm(acc[m][1][r] + bv[1]);
        float Gg = tanh_fast(acc[m][2][r] + bv[2]);
        float Og = sigm(acc[m][3][r] + bv[3]);
        float cn = Fg * cinp[off + U0] + Ig * Gg;
        hp[off + U0] = Og * tanh_fast(cn);
        cp[off + U0] = cn;
      }
      // unit 1 (n4..7 = I,F,G,O)
      {
        float Ig = sigm(acc[m][4][r] + bv[4]);
        float Fg = sigm(acc[m][5][r] + bv[5]);
        float Gg = tanh_fast(acc[m][6][r] + bv[6]);
        float Og = sigm(acc[m][7][r] + bv[7]);
        float cn = Fg * cinp[off + U1] + Ig * Gg;
        hp[off + U1] = Og * tanh_fast(cn);
        cp[off + U1] = cn;
      }
    }
}

extern "C" void kernel_launch(void* const* d_in, const int* in_sizes, int n_in,
                              void* d_out, int out_size, void* d_ws, size_t ws_size,
                              hipStream_t stream) {
  const float* x  = (const float*)d_in[0];
  const float* h  = (const float*)d_in[1];
  const float* c  = (const float*)d_in[2];
  const float* Wi = (const float*)d_in[3];
  const float* bi = (const float*)d_in[4];
  const float* Wh = (const float*)d_in[5];
  const float* bh = (const float*)d_in[6];

  float* out  = (float*)d_out;
  float* Hout = out;
  float* Cout = out + (size_t)BATCH * H_DIM;

  // workspace layout: A bf16 (32 MiB) | Bt bf16 (16 MiB) | bias f32 (16 KiB)
  unsigned short* Abf = (unsigned short*)d_ws;
  unsigned short* Btb = (unsigned short*)((char*)d_ws + 33554432);
  float*          bsf = (float*)((char*)d_ws + 50331648);

  prep_all<<<10256, 256, 0, stream>>>(x, h, Wi, Wh, bi, bh, Abf, Btb, bsf);
  lstm_gemm<<<512, 256, 0, stream>>>(Abf, Btb, bsf, c, Hout, Cout);
}

// Round 15
// 154.041 us; speedup vs baseline: 1.6079x; 1.6079x over previous
//
#include <hip/hip_runtime.h>
#include <stdint.h>

#define IN_DIM 1024
#define H_DIM  1024
#define BATCH  8192
#define KDIM   2048   // IN + H
#define NDIM   4096   // 4*H
#define BM     256
#define BN     256
#define BK     64
#define NT     (KDIM / BK)   // 32 K-tiles

typedef __bf16 bf16x8 __attribute__((ext_vector_type(8)));
typedef float  f32x4  __attribute__((ext_vector_type(4)));
typedef unsigned int u32;

static __device__ __forceinline__ unsigned short f2bf(float f) {
  u32 u = __builtin_bit_cast(u32, f);
  u += 0x7FFFu + ((u >> 16) & 1u);   // round-to-nearest-even
  return (unsigned short)(u >> 16);
}

static __device__ __forceinline__ float sigm(float x) {
  return 1.0f / (1.0f + __expf(-x));
}
static __device__ __forceinline__ float tanh_fast(float x) {
  float e = __expf(-2.0f * fabsf(x));     // in (0,1], no overflow
  float t = (1.0f - e) / (1.0f + e);
  return copysignf(t, x);
}

// ---- fused prep: one dispatch does A-convert, Bt-permute, bias (R12) ----
__global__ void prep_all(const float* __restrict__ x, const float* __restrict__ h,
                         const float* __restrict__ Wi, const float* __restrict__ Wh,
                         const float* __restrict__ bi, const float* __restrict__ bh,
                         unsigned short* __restrict__ A,
                         unsigned short* __restrict__ Bt,
                         float* __restrict__ bias) {
  __shared__ float tile[32][33];
  const int b = blockIdx.x;
  const int t = threadIdx.x;

  if (b < 2048) {
    const int total = BATCH * KDIM / 4;
    for (int i = b * 256 + t; i < total; i += 2048 * 256) {
      int bb = i >> 9;             // 512 quads per row
      int k = (i & 511) << 2;
      const float* src = (k < IN_DIM) ? (x + (size_t)bb * IN_DIM + k)
                                      : (h + (size_t)bb * H_DIM + (k - IN_DIM));
      float4 v = *reinterpret_cast<const float4*>(src);
      ushort4 o;
      o.x = f2bf(v.x); o.y = f2bf(v.y); o.z = f2bf(v.z); o.w = f2bf(v.w);
      *reinterpret_cast<ushort4*>(A + (size_t)bb * KDIM + k) = o;
    }
  } else if (b < 10240) {
    int bb = b - 2048;
    int k0 = (bb & 63) * 32;           // k of combined [Wi;Wh]
    int c0 = (bb >> 6) * 32;           // orig col
    int tx = t & 31;
    int ty = t >> 5;                   // 0..7
    const float* src = (k0 < IN_DIM) ? (Wi + (size_t)k0 * NDIM)
                                     : (Wh + (size_t)(k0 - IN_DIM) * NDIM);
    for (int i = 0; i < 4; i++) {
      int r = ty + 8 * i;
      tile[r][tx] = src[(size_t)r * NDIM + c0 + tx];
    }
    __syncthreads();
    int g = c0 >> 10;                  // gate index (tile doesn't straddle)
    int ubase = c0 & 1023;
    for (int i = 0; i < 4; i++) {
      int cc = ty + 8 * i;
      int u = ubase + cc;
      int j = ((u >> 4) << 6) + (g << 4) + (u & 15);
      Bt[(size_t)j * KDIM + k0 + tx] = f2bf(tile[tx][cc]);
    }
  } else {
    int j = (b - 10240) * 256 + t;     // < 4096
    int u = ((j >> 6) << 4) + (j & 15);
    int g = (j >> 4) & 3;
    int c = (g << 10) + u;
    bias[j] = bi[c] + bh[c];
  }
}

// ------- 256x256 GEMM, 2-barrier/K-tile, balanced post-gate reads (R15) -----
static __device__ __forceinline__ void gload_lds16(const void* g, void* l) {
  __builtin_amdgcn_global_load_lds(
      (const __attribute__((address_space(1))) u32*)g,
      (__attribute__((address_space(3))) u32*)l, 16, 0, 0);
}

#define MFMA __builtin_amdgcn_mfma_f32_16x16x32_bf16
#define SGB  __builtin_amdgcn_sched_group_barrier
// LLVM SchedGroupMask: MFMA=0x8, DS_READ=0x100

__launch_bounds__(512, 2)
__global__ void lstm_gemm(const unsigned short* __restrict__ A,
                          const unsigned short* __restrict__ Bt,
                          const float* __restrict__ bias,
                          const float* __restrict__ Cin,
                          float* __restrict__ Hout,
                          float* __restrict__ Cout) {
  // LDS: A [2 buf][2 half][128 rows][128B] = 64K | B same = 64K  (128 KiB)
  __shared__ __align__(16) char smem[131072];

  const int t  = threadIdx.x;
  const int l  = t & 63;
  const int w  = t >> 6;           // wave 0-7
  const int lane16 = l & 15;
  const int kg = l >> 4;           // 0-3
  const int wr = w >> 2;           // 0-1  (M)
  const int wc = w & 3;            // 0-3  (N)

  int bid = blockIdx.x;            // 512 blocks (32 M-tiles x 16 N-tiles)
  int swz = (bid & 7) * 64 + (bid >> 3);   // bijective XCD swizzle (512%8==0)
  int brow = (swz >> 4) * BM;
  int bcol = (swz & 15) * BN;

  // ---- staging: slot=(w*2+q)*64+l, LDS linear slot*16; global source chunk
  //      pre-swizzled c = (slot&7) ^ (row&7)  (read side XORs the same) ----
  int slot0 = w * 128 + l, slot1 = slot0 + 64;
  int rih0 = slot0 >> 3, rih1 = slot1 >> 3;
  int c0 = (slot0 & 7) ^ (rih0 & 7), c1 = (slot1 & 7) ^ (rih1 & 7);

  // 8 rolling global pointers (A/B x half0/1 x slot q0/q1), bumped 64 elem/K-tile
  const unsigned short* a0q0 = A + (size_t)(brow + (rih0 >> 6) * 128 + (rih0 & 63)) * KDIM + c0 * 8;
  const unsigned short* a0q1 = A + (size_t)(brow + (rih1 >> 6) * 128 + (rih1 & 63)) * KDIM + c1 * 8;
  const unsigned short* a1q0 = a0q0 + 131072;   // +64 rows
  const unsigned short* a1q1 = a0q1 + 131072;
  const unsigned short* b0q0 = Bt + (size_t)(bcol + (rih0 >> 5) * 64 + (rih0 & 31)) * KDIM + c0 * 8;
  const unsigned short* b0q1 = Bt + (size_t)(bcol + (rih1 >> 5) * 64 + (rih1 & 31)) * KDIM + c1 * 8;
  const unsigned short* b1q0 = b0q0 + 65536;    // +32 rows
  const unsigned short* b1q1 = b0q1 + 65536;

#define GL(gp, loff) gload_lds16((gp), smem + (loff) + w * 2048 + l * 16)

  // ---- per-lane ds_read base addresses; everything else folds to offset: ----
  const int msk = (lane16 & 7) << 4;
  char* vA0 = smem + wr * 8192 + lane16 * 128 + ((kg * 16) ^ msk);
  char* vA1 = smem + wr * 8192 + lane16 * 128 + ((64 + kg * 16) ^ msk);
  char* vB0 = smem + 65536 + wc * 4096 + lane16 * 128 + ((kg * 16) ^ msk);
  char* vB1 = smem + 65536 + wc * 4096 + lane16 * 128 + ((64 + kg * 16) ^ msk);

  f32x4 acc[8][4];
#pragma unroll
  for (int m = 0; m < 8; m++)
#pragma unroll
    for (int n = 0; n < 4; n++) acc[m][n] = (f32x4){0.f, 0.f, 0.f, 0.f};

  // ---- prologue: tile0 full -> buf0 ; tile1 {A0,B0} -> buf1 ----
  GL(a0q0, 0);                 GL(a0q1, 1024);
  GL(b0q0, 65536);             GL(b0q1, 65536 + 1024);
  GL(a1q0, 16384);             GL(a1q1, 16384 + 1024);
  GL(b1q0, 65536 + 16384);     GL(b1q1, 65536 + 16384 + 1024);
  GL(a0q0 + 64, 32768);        GL(a0q1 + 64, 32768 + 1024);
  GL(b0q0 + 64, 65536 + 32768);GL(b0q1 + 64, 65536 + 32768 + 1024);
  asm volatile("s_waitcnt vmcnt(4)" ::: "memory");   // tile0 landed
  __builtin_amdgcn_s_barrier();
  __builtin_amdgcn_sched_barrier(0);
  // A1(1) -> buf1 (post-barrier slot of the virtual body(-1))
  GL(a1q0 + 64, 32768 + 16384); GL(a1q1 + 64, 32768 + 16384 + 1024);

  // ---- operand registers. bfrLo (n0-1) is P-keyed double-buffered:
  //      set A serves even tiles, set B odd tiles (loaded one tile ahead
  //      in Q3). afrA/afrB/bfrHi rotate as in R12 (lifetimes traced). ----
  bf16x8 afrA[4][2], afrB[4][2], bfrHi[2][2], bfrLoA[2][2], bfrLoB[2][2];

  // prime: afrA = A0(0), bfrLoA = B0(0) n0-1 from buf0
#pragma unroll
  for (int mm = 0; mm < 4; mm++) {
    afrA[mm][0] = *(const bf16x8*)(vA0 + mm * 2048);
    afrA[mm][1] = *(const bf16x8*)(vA1 + mm * 2048);
  }
#pragma unroll
  for (int nn = 0; nn < 2; nn++) {
    bfrLoA[nn][0] = *(const bf16x8*)(vB0 + nn * 2048);
    bfrLoA[nn][1] = *(const bf16x8*)(vB1 + nn * 2048);
  }
  // roll: a*,b0 -> tile2 ; b1 -> tile1
  a0q0 += 128; a0q1 += 128; a1q0 += 128; a1q1 += 128;
  b0q0 += 128; b0q1 += 128; b1q0 += 64;  b1q1 += 64;

  // ---- 2-barrier K-tile body (R15): gate moved BEFORE Q3 so the 12
  //      post-gate reads split 4 (Q3: B0(t+1) n0-1) + 8 (Q4: A0(t+1)).
  //      FIFO at gate (after S3): [... S4(t-1), S1(t), S2(t), S3(t)] ->
  //      vmcnt(4) drains tile t+1 exactly (A0:S2(t-1), B0:S3(t-1),
  //      A1:S4(t-1), B1:S1(t)) keeping S2(t),S3(t). Hazards as R12;
  //      Q3's B0(t+1) read is gate-covered; its overwrite S3(t+1) is
  //      behind bar_A(t+1) which is behind Q1(t+1)'s lgkm use. ----
#define BODY(P, BLC, BLN)                                                    \
  {                                                                          \
    /* S1: stage B1(t+1) -> buf^1 */                                         \
    GL(b1q0, 65536 + ((P)^1)*32768 + 16384);                                 \
    GL(b1q1, 65536 + ((P)^1)*32768 + 16384 + 1024);                          \
    /* Q1 cluster: MFMA(afrA, BLC) ∥ read bfrHi(t) */                        \
    __builtin_amdgcn_s_setprio(1);                                           \
    _Pragma("unroll") for (int nn = 0; nn < 2; nn++) {                       \
      bfrHi[nn][0] = *(const bf16x8*)(vB0 + (P)*32768 + 16384 + nn*2048);    \
      bfrHi[nn][1] = *(const bf16x8*)(vB1 + (P)*32768 + 16384 + nn*2048);    \
    }                                                                        \
    _Pragma("unroll") for (int mm = 0; mm < 4; mm++)                         \
      _Pragma("unroll") for (int nn = 0; nn < 2; nn++) {                     \
        acc[mm][nn] = MFMA(afrA[mm][0], BLC[nn][0], acc[mm][nn], 0, 0, 0);   \
        acc[mm][nn] = MFMA(afrA[mm][1], BLC[nn][1], acc[mm][nn], 0, 0, 0);   \
      }                                                                      \
    SGB(0x100, 1, 0); SGB(0x8, 4, 0);                                        \
    SGB(0x100, 1, 0); SGB(0x8, 4, 0);                                        \
    SGB(0x100, 1, 0); SGB(0x8, 4, 0);                                        \
    SGB(0x100, 1, 0); SGB(0x8, 4, 0);                                        \
    __builtin_amdgcn_s_setprio(0);                                           \
    __builtin_amdgcn_s_barrier();          /* bar_A */                       \
    __builtin_amdgcn_sched_barrier(0);                                       \
    /* S2: stage A0(t+2) -> buf P */                                         \
    GL(a0q0, (P)*32768);                                                     \
    GL(a0q1, (P)*32768 + 1024);                                              \
    /* Q2 cluster: MFMA(afrA, bfrHi) ∥ read afrB = A1(t) */                  \
    __builtin_amdgcn_s_setprio(1);                                           \
    _Pragma("unroll") for (int mm = 0; mm < 4; mm++) {                       \
      afrB[mm][0] = *(const bf16x8*)(vA0 + (P)*32768 + 16384 + mm*2048);     \
      afrB[mm][1] = *(const bf16x8*)(vA1 + (P)*32768 + 16384 + mm*2048);     \
    }                                                                        \
    _Pragma("unroll") for (int mm = 0; mm < 4; mm++)                         \
      _Pragma("unroll") for (int nn = 2; nn < 4; nn++) {                     \
        acc[mm][nn] = MFMA(afrA[mm][0], bfrHi[nn-2][0], acc[mm][nn], 0, 0, 0);\
        acc[mm][nn] = MFMA(afrA[mm][1], bfrHi[nn-2][1], acc[mm][nn], 0, 0, 0);\
      }                                                                      \
    SGB(0x100, 2, 0); SGB(0x8, 4, 0);                                        \
    SGB(0x100, 2, 0); SGB(0x8, 4, 0);                                        \
    SGB(0x100, 2, 0); SGB(0x8, 4, 0);                                        \
    SGB(0x100, 2, 0); SGB(0x8, 4, 0);                                        \
    __builtin_amdgcn_s_setprio(0);                                           \
    /* S3: stage B0(t+2) -> buf P (BLC readers drained by Q1 MFMAs) */       \
    GL(b0q0, 65536 + (P)*32768);                                             \
    GL(b0q1, 65536 + (P)*32768 + 1024);                                      \
    /* gate: drain tile t+1 (keep A0,B0(t+2) in flight) */                   \
    asm volatile("s_waitcnt vmcnt(4)" ::: "memory");                         \
    __builtin_amdgcn_s_barrier();          /* bar_B */                       \
    __builtin_amdgcn_sched_barrier(0);                                       \
    /* S4: stage A1(t+2) -> buf P (afrB(t) reads drained pre-bar_B) */       \
    GL(a1q0, (P)*32768 + 16384);                                             \
    GL(a1q1, (P)*32768 + 16384 + 1024);                                      \
    /* Q3 cluster: MFMA(afrB, BLC) ∥ read BLN = B0(t+1) n0-1 */              \
    __builtin_amdgcn_s_setprio(1);                                           \
    _Pragma("unroll") for (int nn = 0; nn < 2; nn++) {                       \
      BLN[nn][0] = *(const bf16x8*)(vB0 + ((P)^1)*32768 + nn*2048);          \
      BLN[nn][1] = *(const bf16x8*)(vB1 + ((P)^1)*32768 + nn*2048);          \
    }                                                                        \
    _Pragma("unroll") for (int mm = 0; mm < 4; mm++)                         \
      _Pragma("unroll") for (int nn = 0; nn < 2; nn++) {                     \
        acc[4+mm][nn] = MFMA(afrB[mm][0], BLC[nn][0], acc[4+mm][nn], 0, 0, 0);\
        acc[4+mm][nn] = MFMA(afrB[mm][1], BLC[nn][1], acc[4+mm][nn], 0, 0, 0);\
      }                                                                      \
    SGB(0x100, 1, 0); SGB(0x8, 4, 0);                                        \
    SGB(0x100, 1, 0); SGB(0x8, 4, 0);                                        \
    SGB(0x100, 1, 0); SGB(0x8, 4, 0);                                        \
    SGB(0x100, 1, 0); SGB(0x8, 4, 0);                                        \
    __builtin_amdgcn_s_setprio(0);                                           \
    /* Q4 cluster: MFMA(afrB, bfrHi) ∥ read afrA = A0(t+1) */                \
    __builtin_amdgcn_s_setprio(1);                                           \
    _Pragma("unroll") for (int mm = 0; mm < 4; mm++) {                       \
      afrA[mm][0] = *(const bf16x8*)(vA0 + ((P)^1)*32768 + mm*2048);         \
      afrA[mm][1] = *(const bf16x8*)(vA1 + ((P)^1)*32768 + mm*2048);         \
    }                                                                        \
    _Pragma("unroll") for (int mm = 0; mm < 4; mm++)                         \
      _Pragma("unroll") for (int nn = 2; nn < 4; nn++) {                     \
        acc[4+mm][nn] = MFMA(afrB[mm][0], bfrHi[nn-2][0], acc[4+mm][nn], 0, 0, 0);\
        acc[4+mm][nn] = MFMA(afrB[mm][1], bfrHi[nn-2][1], acc[4+mm][nn], 0, 0, 0);\
      }                                                                      \
    SGB(0x100, 2, 0); SGB(0x8, 4, 0);                                        \
    SGB(0x100, 2, 0); SGB(0x8, 4, 0);                                        \
    SGB(0x100, 2, 0); SGB(0x8, 4, 0);                                        \
    SGB(0x100, 2, 0); SGB(0x8, 4, 0);                                        \
    __builtin_amdgcn_s_setprio(0);                                           \
    a0q0 += 64; a0q1 += 64; a1q0 += 64; a1q1 += 64;                          \
    b0q0 += 64; b0q1 += 64; b1q0 += 64; b1q1 += 64;                          \
  }

  for (int it = 0; it < NT / 2; ++it) {
    BODY(0, bfrLoA, bfrLoB)
    BODY(1, bfrLoB, bfrLoA)
  }
#undef BODY
#undef GL

  // ---- epilogue: issue Cin/bias loads FIRST (latency hides under the
  //      staging drain), then drain everything, then register-only gates. ----
  const int U = (bcol >> 2) + wc * 16 + lane16;     // unit owned by this lane
  const float* cinp = Cin + (size_t)(brow + wr * 128 + kg * 4) * H_DIM + U;
  float cin[32];
#pragma unroll
  for (int m = 0; m < 8; m++)
#pragma unroll
    for (int r = 0; r < 4; r++)
      cin[m * 4 + r] = cinp[(size_t)(m * 16 + r) * H_DIM];
  float bv[4];
#pragma unroll
  for (int nn = 0; nn < 4; nn++)
    bv[nn] = bias[bcol + wc * 64 + nn * 16 + lane16];

  asm volatile("s_waitcnt vmcnt(0)" ::: "memory");

  float* hp = Hout + (size_t)(brow + wr * 128 + kg * 4) * H_DIM + U;
  float* cp = Cout + (size_t)(brow + wr * 128 + kg * 4) * H_DIM + U;
#pragma unroll
  for (int m = 0; m < 8; m++)
#pragma unroll
    for (int r = 0; r < 4; r++) {
      float Ig = sigm(acc[m][0][r] + bv[0]);
      float Fg = sigm(acc[m][1][r] + bv[1]);
      float Gg = tanh_fast(acc[m][2][r] + bv[2]);
      float Og = sigm(acc[m][3][r] + bv[3]);
      float cn = Fg * cin[m * 4 + r] + Ig * Gg;
      size_t off = (size_t)(m * 16 + r) * H_DIM;
      hp[off] = Og * tanh_fast(cn);
      cp[off] = cn;
    }
}

extern "C" void kernel_launch(void* const* d_in, const int* in_sizes, int n_in,
                              void* d_out, int out_size, void* d_ws, size_t ws_size,
                              hipStream_t stream) {
  const float* x  = (const float*)d_in[0];
  const float* h  = (const float*)d_in[1];
  const float* c  = (const float*)d_in[2];
  const float* Wi = (const float*)d_in[3];
  const float* bi = (const float*)d_in[4];
  const float* Wh = (const float*)d_in[5];
  const float* bh = (const float*)d_in[6];

  float* out  = (float*)d_out;
  float* Hout = out;
  float* Cout = out + (size_t)BATCH * H_DIM;

  // workspace layout: A bf16 (32 MiB) | Bt bf16 (16 MiB) | bias f32 (16 KiB)
  unsigned short* Abf = (unsigned short*)d_ws;
  unsigned short* Btb = (unsigned short*)((char*)d_ws + 33554432);
  float*          bsf = (float*)((char*)d_ws + 50331648);

  prep_all<<<10256, 256, 0, stream>>>(x, h, Wi, Wh, bi, bh, Abf, Btb, bsf);
  lstm_gemm<<<512, 512, 0, stream>>>(Abf, Btb, bsf, c, Hout, Cout);
}

// Round 16
// 153.594 us; speedup vs baseline: 1.6125x; 1.0029x over previous
//
#include <hip/hip_runtime.h>
#include <stdint.h>

#define IN_DIM 1024
#define H_DIM  1024
#define BATCH  8192
#define KDIM   2048   // IN + H
#define NDIM   4096   // 4*H
#define BM     256
#define BN     256
#define BK     64
#define NT     (KDIM / BK)   // 32 K-tiles

typedef __bf16 bf16x8 __attribute__((ext_vector_type(8)));
typedef float  f32x4  __attribute__((ext_vector_type(4)));
typedef unsigned int u32;

static __device__ __forceinline__ unsigned short f2bf(float f) {
  u32 u = __builtin_bit_cast(u32, f);
  u += 0x7FFFu + ((u >> 16) & 1u);   // round-to-nearest-even
  return (unsigned short)(u >> 16);
}

static __device__ __forceinline__ float sigm(float x) {
  return 1.0f / (1.0f + __expf(-x));
}
static __device__ __forceinline__ float tanh_fast(float x) {
  float e = __expf(-2.0f * fabsf(x));     // in (0,1], no overflow
  float t = (1.0f - e) / (1.0f + e);
  return copysignf(t, x);
}

// ---- fused prep: one dispatch does A-convert, Bt-permute, bias (R12) ----
__global__ void prep_all(const float* __restrict__ x, const float* __restrict__ h,
                         const float* __restrict__ Wi, const float* __restrict__ Wh,
                         const float* __restrict__ bi, const float* __restrict__ bh,
                         unsigned short* __restrict__ A,
                         unsigned short* __restrict__ Bt,
                         float* __restrict__ bias) {
  __shared__ float tile[32][33];
  const int b = blockIdx.x;
  const int t = threadIdx.x;

  if (b < 2048) {
    const int total = BATCH * KDIM / 4;
    for (int i = b * 256 + t; i < total; i += 2048 * 256) {
      int bb = i >> 9;             // 512 quads per row
      int k = (i & 511) << 2;
      const float* src = (k < IN_DIM) ? (x + (size_t)bb * IN_DIM + k)
                                      : (h + (size_t)bb * H_DIM + (k - IN_DIM));
      float4 v = *reinterpret_cast<const float4*>(src);
      ushort4 o;
      o.x = f2bf(v.x); o.y = f2bf(v.y); o.z = f2bf(v.z); o.w = f2bf(v.w);
      *reinterpret_cast<ushort4*>(A + (size_t)bb * KDIM + k) = o;
    }
  } else if (b < 10240) {
    int bb = b - 2048;
    int k0 = (bb & 63) * 32;           // k of combined [Wi;Wh]
    int c0 = (bb >> 6) * 32;           // orig col
    int tx = t & 31;
    int ty = t >> 5;                   // 0..7
    const float* src = (k0 < IN_DIM) ? (Wi + (size_t)k0 * NDIM)
                                     : (Wh + (size_t)(k0 - IN_DIM) * NDIM);
    for (int i = 0; i < 4; i++) {
      int r = ty + 8 * i;
      tile[r][tx] = src[(size_t)r * NDIM + c0 + tx];
    }
    __syncthreads();
    int g = c0 >> 10;                  // gate index (tile doesn't straddle)
    int ubase = c0 & 1023;
    for (int i = 0; i < 4; i++) {
      int cc = ty + 8 * i;
      int u = ubase + cc;
      int j = ((u >> 4) << 6) + (g << 4) + (u & 15);
      Bt[(size_t)j * KDIM + k0 + tx] = f2bf(tile[tx][cc]);
    }
  } else {
    int j = (b - 10240) * 256 + t;     // < 4096
    int u = ((j >> 6) << 4) + (j & 15);
    int g = (j >> 4) & 3;
    int c = (g << 10) + u;
    bias[j] = bi[c] + bh[c];
  }
}

// ------- 256x256 GEMM, 2-barrier/K-tile pipeline + fused LSTM epilogue -------
// (R9 schedule verbatim: best measured — 129 µs, MfmaUtil 48%, 0 conflicts)
static __device__ __forceinline__ void gload_lds16(const void* g, void* l) {
  __builtin_amdgcn_global_load_lds(
      (const __attribute__((address_space(1))) u32*)g,
      (__attribute__((address_space(3))) u32*)l, 16, 0, 0);
}

#define MFMA __builtin_amdgcn_mfma_f32_16x16x32_bf16
#define SGB  __builtin_amdgcn_sched_group_barrier
// LLVM SchedGroupMask: MFMA=0x8, DS_READ=0x100

__launch_bounds__(512, 2)
__global__ void lstm_gemm(const unsigned short* __restrict__ A,
                          const unsigned short* __restrict__ Bt,
                          const float* __restrict__ bias,
                          const float* __restrict__ Cin,
                          float* __restrict__ Hout,
                          float* __restrict__ Cout) {
  // LDS: A [2 buf][2 half][128 rows][128B] = 64K | B same = 64K  (128 KiB)
  __shared__ __align__(16) char smem[131072];

  const int t  = threadIdx.x;
  const int l  = t & 63;
  const int w  = t >> 6;           // wave 0-7
  const int lane16 = l & 15;
  const int kg = l >> 4;           // 0-3
  const int wr = w >> 2;           // 0-1  (M)
  const int wc = w & 3;            // 0-3  (N)

  int bid = blockIdx.x;            // 512 blocks (32 M-tiles x 16 N-tiles)
  int swz = (bid & 7) * 64 + (bid >> 3);   // bijective XCD swizzle (512%8==0)
  int brow = (swz >> 4) * BM;
  int bcol = (swz & 15) * BN;

  // ---- staging: slot=(w*2+q)*64+l, LDS linear slot*16; global source chunk
  //      pre-swizzled c = (slot&7) ^ (row&7)  (read side XORs the same) ----
  int slot0 = w * 128 + l, slot1 = slot0 + 64;
  int rih0 = slot0 >> 3, rih1 = slot1 >> 3;
  int c0 = (slot0 & 7) ^ (rih0 & 7), c1 = (slot1 & 7) ^ (rih1 & 7);

  // 8 rolling global pointers (A/B x half0/1 x slot q0/q1), bumped 64 elem/K-tile
  const unsigned short* a0q0 = A + (size_t)(brow + (rih0 >> 6) * 128 + (rih0 & 63)) * KDIM + c0 * 8;
  const unsigned short* a0q1 = A + (size_t)(brow + (rih1 >> 6) * 128 + (rih1 & 63)) * KDIM + c1 * 8;
  const unsigned short* a1q0 = a0q0 + 131072;   // +64 rows
  const unsigned short* a1q1 = a0q1 + 131072;
  const unsigned short* b0q0 = Bt + (size_t)(bcol + (rih0 >> 5) * 64 + (rih0 & 31)) * KDIM + c0 * 8;
  const unsigned short* b0q1 = Bt + (size_t)(bcol + (rih1 >> 5) * 64 + (rih1 & 31)) * KDIM + c1 * 8;
  const unsigned short* b1q0 = b0q0 + 65536;    // +32 rows
  const unsigned short* b1q1 = b0q1 + 65536;

#define GL(gp, loff) gload_lds16((gp), smem + (loff) + w * 2048 + l * 16)

  // ---- per-lane ds_read base addresses; everything else folds to offset: ----
  const int msk = (lane16 & 7) << 4;
  char* vA0 = smem + wr * 8192 + lane16 * 128 + ((kg * 16) ^ msk);
  char* vA1 = smem + wr * 8192 + lane16 * 128 + ((64 + kg * 16) ^ msk);
  char* vB0 = smem + 65536 + wc * 4096 + lane16 * 128 + ((kg * 16) ^ msk);
  char* vB1 = smem + 65536 + wc * 4096 + lane16 * 128 + ((64 + kg * 16) ^ msk);

  f32x4 acc[8][4];
#pragma unroll
  for (int m = 0; m < 8; m++)
#pragma unroll
    for (int n = 0; n < 4; n++) acc[m][n] = (f32x4){0.f, 0.f, 0.f, 0.f};

  // ---- prologue: tile0 full -> buf0 ; tile1 {A0,B0} -> buf1 ----
  GL(a0q0, 0);                 GL(a0q1, 1024);
  GL(b0q0, 65536);             GL(b0q1, 65536 + 1024);
  GL(a1q0, 16384);             GL(a1q1, 16384 + 1024);
  GL(b1q0, 65536 + 16384);     GL(b1q1, 65536 + 16384 + 1024);
  GL(a0q0 + 64, 32768);        GL(a0q1 + 64, 32768 + 1024);
  GL(b0q0 + 64, 65536 + 32768);GL(b0q1 + 64, 65536 + 32768 + 1024);
  asm volatile("s_waitcnt vmcnt(4)" ::: "memory");   // tile0 landed
  __builtin_amdgcn_s_barrier();
  __builtin_amdgcn_sched_barrier(0);
  // A1(1) -> buf1 (post-barrier slot of the virtual body(-1))
  GL(a1q0 + 64, 32768 + 16384); GL(a1q1 + 64, 32768 + 16384 + 1024);

  // ---- operand registers (ping-pong lifetimes across quadrant clusters) ----
  bf16x8 afrA[4][2], afrB[4][2], bfr[4][2];

  // prime: afrA = A0(0), bfr01 = B0(0) from buf0
#pragma unroll
  for (int mm = 0; mm < 4; mm++) {
    afrA[mm][0] = *(const bf16x8*)(vA0 + mm * 2048);
    afrA[mm][1] = *(const bf16x8*)(vA1 + mm * 2048);
  }
#pragma unroll
  for (int nn = 0; nn < 2; nn++) {
    bfr[nn][0] = *(const bf16x8*)(vB0 + nn * 2048);
    bfr[nn][1] = *(const bf16x8*)(vB1 + nn * 2048);
  }
  // roll: a*,b0 -> tile2 ; b1 -> tile1
  a0q0 += 128; a0q1 += 128; a1q0 += 128; a1q1 += 128;
  b0q0 += 128; b0q1 += 128; b1q0 += 64;  b1q1 += 64;

  // ---- 2-barrier K-tile body (R9). Sync: bar_A after Q1 cluster;
  //      vmcnt(4)+bar_B before Q4 cluster. Hazards traced; sched_barrier(0)
  //      after each barrier stops GL/ds_read hoisting (rule #18).
#define BODY(P)                                                              \
  {                                                                          \
    /* S1: stage B1(t+1) -> buf^1 (region's last reader drained pre-bar_B) */\
    GL(b1q0, 65536 + ((P)^1)*32768 + 16384);                                 \
    GL(b1q1, 65536 + ((P)^1)*32768 + 16384 + 1024);                          \
    /* Q1 cluster: MFMA(afrA,bfr01) ∥ read bfr23(t) */                       \
    __builtin_amdgcn_s_setprio(1);                                           \
    _Pragma("unroll") for (int nn = 2; nn < 4; nn++) {                       \
      bfr[nn][0] = *(const bf16x8*)(vB0 + (P)*32768 + 16384 + (nn-2)*2048);  \
      bfr[nn][1] = *(const bf16x8*)(vB1 + (P)*32768 + 16384 + (nn-2)*2048);  \
    }                                                                        \
    _Pragma("unroll") for (int mm = 0; mm < 4; mm++)                         \
      _Pragma("unroll") for (int nn = 0; nn < 2; nn++) {                     \
        acc[mm][nn] = MFMA(afrA[mm][0], bfr[nn][0], acc[mm][nn], 0, 0, 0);   \
        acc[mm][nn] = MFMA(afrA[mm][1], bfr[nn][1], acc[mm][nn], 0, 0, 0);   \
      }                                                                      \
    SGB(0x100, 1, 0); SGB(0x8, 4, 0);                                        \
    SGB(0x100, 1, 0); SGB(0x8, 4, 0);                                        \
    SGB(0x100, 1, 0); SGB(0x8, 4, 0);                                        \
    SGB(0x100, 1, 0); SGB(0x8, 4, 0);                                        \
    __builtin_amdgcn_s_setprio(0);                                           \
    __builtin_amdgcn_s_barrier();          /* bar_A */                       \
    __builtin_amdgcn_sched_barrier(0);                                       \
    /* S2: stage A0(t+2) -> buf P (afrA(t) reads drained by Q1 MFMAs) */     \
    GL(a0q0, (P)*32768);                                                     \
    GL(a0q1, (P)*32768 + 1024);                                              \
    /* Q2 cluster: MFMA(afrA,bfr23) ∥ read afrB = A1(t) */                   \
    __builtin_amdgcn_s_setprio(1);                                           \
    _Pragma("unroll") for (int mm = 0; mm < 4; mm++) {                       \
      afrB[mm][0] = *(const bf16x8*)(vA0 + (P)*32768 + 16384 + mm*2048);     \
      afrB[mm][1] = *(const bf16x8*)(vA1 + (P)*32768 + 16384 + mm*2048);     \
    }                                                                        \
    _Pragma("unroll") for (int mm = 0; mm < 4; mm++)                         \
      _Pragma("unroll") for (int nn = 2; nn < 4; nn++) {                     \
        acc[mm][nn] = MFMA(afrA[mm][0], bfr[nn][0], acc[mm][nn], 0, 0, 0);   \
        acc[mm][nn] = MFMA(afrA[mm][1], bfr[nn][1], acc[mm][nn], 0, 0, 0);   \
      }                                                                      \
    SGB(0x100, 2, 0); SGB(0x8, 4, 0);                                        \
    SGB(0x100, 2, 0); SGB(0x8, 4, 0);                                        \
    SGB(0x100, 2, 0); SGB(0x8, 4, 0);                                        \
    SGB(0x100, 2, 0); SGB(0x8, 4, 0);                                        \
    __builtin_amdgcn_s_setprio(0);                                           \
    /* S3: stage B0(t+2) -> buf P (bfr01(t) reads drained by Q1 MFMAs) */    \
    GL(b0q0, 65536 + (P)*32768);                                             \
    GL(b0q1, 65536 + (P)*32768 + 1024);                                      \
    /* Q3 cluster: MFMA(afrB,bfr01), register-only */                        \
    __builtin_amdgcn_s_setprio(1);                                           \
    _Pragma("unroll") for (int mm = 0; mm < 4; mm++)                         \
      _Pragma("unroll") for (int nn = 0; nn < 2; nn++) {                     \
        acc[4+mm][nn] = MFMA(afrB[mm][0], bfr[nn][0], acc[4+mm][nn], 0, 0, 0);\
        acc[4+mm][nn] = MFMA(afrB[mm][1], bfr[nn][1], acc[4+mm][nn], 0, 0, 0);\
      }                                                                      \
    __builtin_amdgcn_s_setprio(0);                                           \
    /* gate: tile t+1 fully landed (FIFO: only A0,B0(t+2) stay outstanding) */\
    asm volatile("s_waitcnt vmcnt(4)" ::: "memory");                         \
    __builtin_amdgcn_s_barrier();          /* bar_B */                       \
    __builtin_amdgcn_sched_barrier(0);                                       \
    /* S4: stage A1(t+2) -> buf P (afrB(t) reads drained pre-bar_B) */       \
    GL(a1q0, (P)*32768 + 16384);                                             \
    GL(a1q1, (P)*32768 + 16384 + 1024);                                      \
    /* Q4 cluster: MFMA(afrB,bfr23) ∥ read afrA,bfr01 of tile t+1 */         \
    __builtin_amdgcn_s_setprio(1);                                           \
    _Pragma("unroll") for (int mm = 0; mm < 4; mm++) {                       \
      afrA[mm][0] = *(const bf16x8*)(vA0 + ((P)^1)*32768 + mm*2048);         \
      afrA[mm][1] = *(const bf16x8*)(vA1 + ((P)^1)*32768 + mm*2048);         \
    }                                                                        \
    _Pragma("unroll") for (int nn = 0; nn < 2; nn++) {                       \
      bfr[nn][0] = *(const bf16x8*)(vB0 + ((P)^1)*32768 + nn*2048);          \
      bfr[nn][1] = *(const bf16x8*)(vB1 + ((P)^1)*32768 + nn*2048);          \
    }                                                                        \
    _Pragma("unroll") for (int mm = 0; mm < 4; mm++)                         \
      _Pragma("unroll") for (int nn = 2; nn < 4; nn++) {                     \
        acc[4+mm][nn] = MFMA(afrB[mm][0], bfr[nn][0], acc[4+mm][nn], 0, 0, 0);\
        acc[4+mm][nn] = MFMA(afrB[mm][1], bfr[nn][1], acc[4+mm][nn], 0, 0, 0);\
      }                                                                      \
    SGB(0x100, 3, 0); SGB(0x8, 4, 0);                                        \
    SGB(0x100, 3, 0); SGB(0x8, 4, 0);                                        \
    SGB(0x100, 3, 0); SGB(0x8, 4, 0);                                        \
    SGB(0x100, 3, 0); SGB(0x8, 4, 0);                                        \
    __builtin_amdgcn_s_setprio(0);                                           \
    a0q0 += 64; a0q1 += 64; a1q0 += 64; a1q1 += 64;                          \
    b0q0 += 64; b0q1 += 64; b1q0 += 64; b1q1 += 64;                          \
  }

  for (int it = 0; it < NT / 2; ++it) {
    BODY(0)
    BODY(1)
  }
#undef BODY
#undef GL

  // ---- drain outstanding staging loads (also orders Cin/bias below) ----
  asm volatile("s_waitcnt vmcnt(0)" ::: "memory");

  // ---- epilogue: register-only gates (lane owns all 4 gates of unit U).
  //      Cin/bias loaded post-loop: no registers held across the main loop.
  const int U = (bcol >> 2) + wc * 16 + lane16;     // unit owned by this lane
  const float* cinp = Cin + (size_t)(brow + wr * 128 + kg * 4) * H_DIM + U;
  float cin[32];
#pragma unroll
  for (int m = 0; m < 8; m++)
#pragma unroll
    for (int r = 0; r < 4; r++)
      cin[m * 4 + r] = cinp[(size_t)(m * 16 + r) * H_DIM];
  float bv[4];
#pragma unroll
  for (int nn = 0; nn < 4; nn++)
    bv[nn] = bias[bcol + wc * 64 + nn * 16 + lane16];

  float* hp = Hout + (size_t)(brow + wr * 128 + kg * 4) * H_DIM + U;
  float* cp = Cout + (size_t)(brow + wr * 128 + kg * 4) * H_DIM + U;
#pragma unroll
  for (int m = 0; m < 8; m++)
#pragma unroll
    for (int r = 0; r < 4; r++) {
      float Ig = sigm(acc[m][0][r] + bv[0]);
      float Fg = sigm(acc[m][1][r] + bv[1]);
      float Gg = tanh_fast(acc[m][2][r] + bv[2]);
      float Og = sigm(acc[m][3][r] + bv[3]);
      float cn = Fg * cin[m * 4 + r] + Ig * Gg;
      size_t off = (size_t)(m * 16 + r) * H_DIM;
      hp[off] = Og * tanh_fast(cn);
      cp[off] = cn;
    }
}

extern "C" void kernel_launch(void* const* d_in, const int* in_sizes, int n_in,
                              void* d_out, int out_size, void* d_ws, size_t ws_size,
                              hipStream_t stream) {
  const float* x  = (const float*)d_in[0];
  const float* h  = (const float*)d_in[1];
  const float* c  = (const float*)d_in[2];
  const float* Wi = (const float*)d_in[3];
  const float* bi = (const float*)d_in[4];
  const float* Wh = (const float*)d_in[5];
  const float* bh = (const float*)d_in[6];

  float* out  = (float*)d_out;
  float* Hout = out;
  float* Cout = out + (size_t)BATCH * H_DIM;

  // workspace layout: A bf16 (32 MiB) | Bt bf16 (16 MiB) | bias f32 (16 KiB)
  unsigned short* Abf = (unsigned short*)d_ws;
  unsigned short* Btb = (unsigned short*)((char*)d_ws + 33554432);
  float*          bsf = (float*)((char*)d_ws + 50331648);

  prep_all<<<10256, 256, 0, stream>>>(x, h, Wi, Wh, bi, bh, Abf, Btb, bsf);
  lstm_gemm<<<512, 512, 0, stream>>>(Abf, Btb, bsf, c, Hout, Cout);
}